// Round 3
// baseline (1705.873 us; speedup 1.0000x reference)
//
#include <hip/hip_runtime.h>

typedef unsigned short ushort_t;
typedef unsigned int uint_t;

typedef __bf16 bf16x8 __attribute__((ext_vector_type(8)));
typedef float  floatx4 __attribute__((ext_vector_type(4)));

#define AS3 __attribute__((address_space(3)))
#define AS1 __attribute__((address_space(1)))

// ---------------- dims ----------------
#define BATCH 512
#define D_IN  120000
#define N1P   640   // 600 padded to 5*128 (cols 600-639 masked downstream)
#define N2P   640
#define N3P   320
#define N4P   256
#define N5P   256

// bucket pipeline for W1 densify
#define SUBS  8      // col sub-blocks per row
#define SUBW  15000  // cols per sub-block (8*15000 = 120000)
#define NBKT  (600 * SUBS)  // 4800
#define BCAP  2048   // mean 1500, sigma ~39 -> overflow probability ~0

// gemm1 split-K (per K-half of 60000): 25 splits * 2400 (=75*32)
#define NSPLIT 25
#define KCHUNK 2400

// ---------------- workspace layout (bytes), total 249,138,944 < proven 280.8 MB ----------------
static constexpr long O_W1  = 0;                         // bf16 [600][120000]
static constexpr long SZ_W1 = 600L * D_IN * 2;           // 144,000,000
static constexpr long O_BKT = O_W1 + SZ_W1;              // u32 [4800][2048]; later aliased by partials
static constexpr long SZ_BKT = (long)NBKT * BCAP * 4;    // 39,321,600
static constexpr long O_PART = O_BKT;                    // f32 [25][512][640] = 32,768,000 (alias)
static constexpr long O_Y1  = O_BKT + SZ_BKT;            // f32 [512][640]
static constexpr long SZ_Y1 = 512L * N1P * 4;            // 1,310,720
static constexpr long O_W2  = O_Y1 + SZ_Y1;              // f32 [640][640]
static constexpr long SZ_W2 = 640L * 640 * 4;
static constexpr long O_W3  = O_W2 + SZ_W2;              // f32 [320][640]
static constexpr long SZ_W3 = 320L * 640 * 4;
static constexpr long O_W4  = O_W3 + SZ_W3;              // f32 [256][320]
static constexpr long SZ_W4 = 256L * 320 * 4;
static constexpr long O_W5  = O_W4 + SZ_W4;              // f32 [256][256]
static constexpr long SZ_W5 = 256L * 256 * 4;
static constexpr long O_CUR = O_W5 + SZ_W5;              // i32 [4800]
static constexpr long SZ_CUR = (long)NBKT * 4;           // 19,200
static constexpr long ZERO_OFF = O_W2;                   // zero W2..W5 + cursors (contiguous)
static constexpr long ZERO_BYTES = SZ_W2 + SZ_W3 + SZ_W4 + SZ_W5 + SZ_CUR;  // 3,066,624
static constexpr long O_XB  = O_CUR + SZ_CUR;            // bf16 [512][60000] (K-half staging)
static constexpr long SZ_XB = 512L * 60000 * 2;          // 61,440,000
// h-buffers alias Xb (dead after 2nd gemm half)
static constexpr long O_H1 = O_XB;
static constexpr long O_H2 = O_H1 + 512L * 640 * 4;
static constexpr long O_Y3 = O_H2 + 512L * 640 * 4;
static constexpr long O_H3 = O_Y3 + 512L * 320 * 4;
static constexpr long O_Y4 = O_H3 + 512L * 320 * 4;
static constexpr long O_H4 = O_Y4 + 512L * 256 * 4;

// ---------------- helpers ----------------
__device__ __forceinline__ ushort_t f2bf(float f) {
    union { float f; uint_t u; } x;
    x.f = f;
    uint_t u = x.u;
    return (ushort_t)((u + 0x7FFFu + ((u >> 16) & 1u)) >> 16);  // RNE
}
__device__ __forceinline__ float bf2f(ushort_t h) {
    union { uint_t u; float f; } x;
    x.u = ((uint_t)h) << 16;
    return x.f;
}
__device__ __forceinline__ float silu_f(float z) {
    return z / (1.f + expf(-z));
}
__device__ __forceinline__ void load16_lds(const void* g, void* l) {
    __builtin_amdgcn_global_load_lds((const AS1 char*)g, (AS3 char*)l, 16, 0, 0);
}

// ---------------- zero (W2..W5 + cursors) ----------------
__global__ void zero_f4(float4* __restrict__ p, long n4) {
    long i = (long)blockIdx.x * blockDim.x + threadIdx.x;
    if (i < n4) p[i] = make_float4(0.f, 0.f, 0.f, 0.f);
}

// ---------------- reorder nnz1 into (row, col-subblock) buckets ----------------
__global__ void reorder(const int* __restrict__ idx, const float* __restrict__ vals,
                        int nnz, uint_t* __restrict__ bkt, int* __restrict__ cur) {
    int i = blockIdx.x * blockDim.x + threadIdx.x;
    if (i >= nnz) return;
    int r = idx[i];
    int c = idx[nnz + i];
    int q = c / SUBW;
    int b = r * SUBS + q;
    int colw = c - q * SUBW;
    int pos = atomicAdd(&cur[b], 1);
    if (pos < BCAP)
        bkt[(size_t)b * BCAP + pos] = ((uint_t)colw << 16) | (uint_t)f2bf(vals[i]);
}

// ---------------- fill W1: one block per bucket; LDS f32 accumulate -> bf16 stream ----------------
__global__ __launch_bounds__(256) void fill_w1(const uint_t* __restrict__ bkt,
                                               const int* __restrict__ cur,
                                               ushort_t* __restrict__ W) {
    __shared__ float acc[SUBW];  // 60,000 B
    const int b = blockIdx.x;
    const int t = threadIdx.x;
    for (int i = t; i < SUBW; i += 256) acc[i] = 0.f;
    __syncthreads();
    int cnt = cur[b];
    if (cnt > BCAP) cnt = BCAP;
    const uint_t* p = bkt + (size_t)b * BCAP;
    for (int i = t; i < cnt; i += 256) {
        uint_t e = p[i];
        atomicAdd(&acc[e >> 16], bf2f((ushort_t)(e & 0xFFFFu)));
    }
    __syncthreads();
    const int r = b >> 3, sub = b & 7;
    ushort_t* dst = W + (size_t)r * D_IN + sub * SUBW;
    for (int i = t; i < SUBW / 8; i += 256) {  // 1875 16B chunks
        union { ushort_t us[8]; uint4 v; } u;
#pragma unroll
        for (int k = 0; k < 8; k++) u.us[k] = f2bf(acc[i * 8 + k]);
        ((uint4*)dst)[i] = u.v;
    }
}

// ---------------- scatter small layers into dense fp32 W ----------------
__global__ void scatter_f32(const int* __restrict__ idx, const float* __restrict__ vals,
                            int nnz, float* __restrict__ W, int ldw) {
    int i = blockIdx.x * blockDim.x + threadIdx.x;
    if (i >= nnz) return;
    atomicAdd(&W[(size_t)idx[i] * ldw + idx[nnz + i]], vals[i]);
}

// ---------------- cast one K-half of x: fp32 -> bf16 [512][60000] ----------------
__global__ void cast_half(const float* __restrict__ X, int kbase, ushort_t* __restrict__ Xb) {
    long t = (long)blockIdx.x * blockDim.x + threadIdx.x;
    if (t >= (long)BATCH * 7500) return;
    int row = (int)(t / 7500);
    int c8 = (int)(t - (long)row * 7500);
    const float4* s = (const float4*)(X + (size_t)row * D_IN + kbase + c8 * 8);
    float4 a = s[0], bb = s[1];
    union { ushort_t us[8]; uint4 v; } u;
    u.us[0] = f2bf(a.x);  u.us[1] = f2bf(a.y);  u.us[2] = f2bf(a.z);  u.us[3] = f2bf(a.w);
    u.us[4] = f2bf(bb.x); u.us[5] = f2bf(bb.y); u.us[6] = f2bf(bb.z); u.us[7] = f2bf(bb.w);
    ((uint4*)Xb)[t] = u.v;
}

// ---------------- GEMM1 half: P[s] (+)= Xb(512x60000,bf16) @ W1^T rows, K-chunk per split ----------------
// grid = (20 tiles = 4m x 5n, 25 splits), block = 256
__global__ __launch_bounds__(256) void gemm1(const ushort_t* __restrict__ X, int ldx,
                                             const ushort_t* __restrict__ W, int kwbase,
                                             float* __restrict__ P, int accum) {
    __shared__ ushort_t sA[128 * 32];
    __shared__ ushort_t sB[128 * 32];

    const int tile = blockIdx.x;
    const int bm = tile / 5, bn = tile % 5;
    const int ks = blockIdx.y * KCHUNK;

    const int t = threadIdx.x;
    const int lane = t & 63;
    const int w = t >> 6;
    const int wm = w >> 1, wn = w & 1;

    const int c0 = w * 128 + lane;
    const int c1 = c0 + 64;
    const int rA0 = c0 >> 2, qA0 = c0 & 3;
    const int rA1 = c1 >> 2, qA1 = c1 & 3;

    const ushort_t* pa0 = X + (size_t)(bm * 128 + rA0) * ldx + ks + qA0 * 8;
    const ushort_t* pa1 = X + (size_t)(bm * 128 + rA1) * ldx + ks + qA1 * 8;
    const ushort_t* pb0 = W + (size_t)(bn * 128 + rA0) * D_IN + kwbase + ks + qA0 * 8;
    const ushort_t* pb1 = W + (size_t)(bn * 128 + rA1) * D_IN + kwbase + ks + qA1 * 8;

    ushort_t* la0 = sA + (size_t)(w * 128) * 8;
    ushort_t* la1 = sA + (size_t)(w * 128 + 64) * 8;
    ushort_t* lb0 = sB + (size_t)(w * 128) * 8;
    ushort_t* lb1 = sB + (size_t)(w * 128 + 64) * 8;

    const int i16 = lane & 15;
    const int qk = lane >> 4;
    const bf16x8* ap[4];
    const bf16x8* bp[4];
#pragma unroll
    for (int mi = 0; mi < 4; mi++)
        ap[mi] = (const bf16x8*)&sA[(size_t)(wm * 64 + mi * 16 + i16) * 32 + qk * 8];
#pragma unroll
    for (int ni = 0; ni < 4; ni++)
        bp[ni] = (const bf16x8*)&sB[(size_t)(wn * 64 + ni * 16 + i16) * 32 + qk * 8];

    floatx4 acc[4][4] = {};

    for (int it = 0; it < KCHUNK / 32; ++it) {
        __syncthreads();
        load16_lds(pa0, la0);
        load16_lds(pa1, la1);
        load16_lds(pb0, lb0);
        load16_lds(pb1, lb1);
        pa0 += 32; pa1 += 32; pb0 += 32; pb1 += 32;
        __syncthreads();

        bf16x8 af[4], bfr[4];
#pragma unroll
        for (int mi = 0; mi < 4; mi++) af[mi] = *ap[mi];
#pragma unroll
        for (int ni = 0; ni < 4; ni++) bfr[ni] = *bp[ni];
#pragma unroll
        for (int mi = 0; mi < 4; mi++)
#pragma unroll
            for (int ni = 0; ni < 4; ni++)
                acc[mi][ni] = __builtin_amdgcn_mfma_f32_16x16x32_bf16(af[mi], bfr[ni], acc[mi][ni], 0, 0, 0);
    }

    // epilogue: per-split partial store (C/D: col = lane&15, row = (lane>>4)*4 + reg)
    float* Pp = P + (size_t)blockIdx.y * (512 * N1P);
#pragma unroll
    for (int mi = 0; mi < 4; mi++) {
#pragma unroll
        for (int ni = 0; ni < 4; ni++) {
#pragma unroll
            for (int r = 0; r < 4; r++) {
                int row = bm * 128 + wm * 64 + mi * 16 + qk * 4 + r;
                int col = bn * 128 + wn * 64 + ni * 16 + i16;
                size_t o = (size_t)row * N1P + col;
                if (accum) Pp[o] += acc[mi][ni][r];
                else       Pp[o]  = acc[mi][ni][r];
            }
        }
    }
}

// ---------------- reduce split-K partials -> y1 ----------------
__global__ void reduce_part(const float* __restrict__ P, float* __restrict__ Y) {
    int i = blockIdx.x * 256 + threadIdx.x;  // 327,680 total
    float s = 0.f;
#pragma unroll
    for (int k = 0; k < NSPLIT; k++) s += P[(size_t)k * (512 * N1P) + i];
    Y[i] = s;
}

// ---------------- BatchNorm (training, biased var) + SiLU, per-column ----------------
__global__ void bn_silu(const float* __restrict__ Y, int ld, int realN,
                        const float* __restrict__ g, const float* __restrict__ be,
                        float* __restrict__ H) {
    int j = blockIdx.x;
    int t = threadIdx.x;
    if (j >= realN) {
        for (int b = t; b < BATCH; b += 256) H[(size_t)b * ld + j] = 0.f;
        return;
    }
    float v0 = Y[(size_t)t * ld + j];
    float v1 = Y[(size_t)(t + 256) * ld + j];
    __shared__ float rs[256], rss[256];
    rs[t] = v0 + v1;
    rss[t] = v0 * v0 + v1 * v1;
    __syncthreads();
    for (int o = 128; o > 0; o >>= 1) {
        if (t < o) { rs[t] += rs[t + o]; rss[t] += rss[t + o]; }
        __syncthreads();
    }
    float mean = rs[0] * (1.f / 512.f);
    float var  = rss[0] * (1.f / 512.f) - mean * mean;
    float sc = rsqrtf(var + 1e-5f) * g[j];
    float sh = be[j] - mean * sc;
    H[(size_t)t * ld + j]         = silu_f(v0 * sc + sh);
    H[(size_t)(t + 256) * ld + j] = silu_f(v1 * sc + sh);
}

// ---------------- small fp32 GEMM: C(512 x N) = A(512 x K) @ W^T(N x K) ----------------
template <int ACT, int GUARD>
__global__ __launch_bounds__(256) void small_gemm(const float* __restrict__ A, int lda,
                                                  const float* __restrict__ W, int ldw,
                                                  const float* __restrict__ bias, int biasN,
                                                  float* __restrict__ out, int ldo, int outN,
                                                  int K) {
    __shared__ float sA[64][20];
    __shared__ float sB[64][20];
    const int t = threadIdx.x;
    const int m0 = blockIdx.x * 64, n0 = blockIdx.y * 64;
    const int ty = t >> 4, tx = t & 15;
    const int lm = t >> 2, lq = t & 3;
    float acc[4][4] = {};

    for (int kt = 0; kt < K; kt += 16) {
        __syncthreads();
        float4 av = *(const float4*)&A[(size_t)(m0 + lm) * lda + kt + lq * 4];
        float4 wv = *(const float4*)&W[(size_t)(n0 + lm) * ldw + kt + lq * 4];
        sA[lm][lq * 4 + 0] = av.x; sA[lm][lq * 4 + 1] = av.y;
        sA[lm][lq * 4 + 2] = av.z; sA[lm][lq * 4 + 3] = av.w;
        sB[lm][lq * 4 + 0] = wv.x; sB[lm][lq * 4 + 1] = wv.y;
        sB[lm][lq * 4 + 2] = wv.z; sB[lm][lq * 4 + 3] = wv.w;
        __syncthreads();
#pragma unroll
        for (int kg = 0; kg < 4; kg++) {
            float4 a4[4], b4[4];
#pragma unroll
            for (int i = 0; i < 4; i++) a4[i] = *(const float4*)&sA[ty * 4 + i][kg * 4];
#pragma unroll
            for (int j = 0; j < 4; j++) b4[j] = *(const float4*)&sB[tx * 4 + j][kg * 4];
#pragma unroll
            for (int i = 0; i < 4; i++)
#pragma unroll
                for (int j = 0; j < 4; j++)
                    acc[i][j] += a4[i].x * b4[j].x + a4[i].y * b4[j].y +
                                 a4[i].z * b4[j].z + a4[i].w * b4[j].w;
        }
    }

#pragma unroll
    for (int i = 0; i < 4; i++) {
#pragma unroll
        for (int j = 0; j < 4; j++) {
            int row = m0 + ty * 4 + i;
            int col = n0 + tx * 4 + j;
            float v = acc[i][j];
            if (bias != nullptr && col < biasN) v += bias[col];
            if (ACT == 1) v = silu_f(v);
            if (GUARD) {
                if (col < outN) out[(size_t)row * ldo + col] = v;
            } else {
                out[(size_t)row * ldo + col] = v;
            }
        }
    }
}

// ---------------- launch ----------------
extern "C" void kernel_launch(void* const* d_in, const int* in_sizes, int n_in,
                              void* d_out, int out_size, void* d_ws, size_t ws_size,
                              hipStream_t stream) {
    const float* x   = (const float*)d_in[0];
    const int* idx1 = (const int*)d_in[1];  const float* val1 = (const float*)d_in[2];
    const int* idx2 = (const int*)d_in[4];  const float* val2 = (const float*)d_in[5];
    const float* b2 = (const float*)d_in[6];
    const int* idx3 = (const int*)d_in[7];  const float* val3 = (const float*)d_in[8];
    const int* idx4 = (const int*)d_in[10]; const float* val4 = (const float*)d_in[11];
    const int* idx5 = (const int*)d_in[13]; const float* val5 = (const float*)d_in[14];
    const float* b5 = (const float*)d_in[15];
    const float* g1 = (const float*)d_in[16]; const float* be1 = (const float*)d_in[17];
    const float* g2 = (const float*)d_in[18]; const float* be2 = (const float*)d_in[19];
    const float* g3 = (const float*)d_in[20]; const float* be3 = (const float*)d_in[21];

    const int nnz1 = in_sizes[1] / 2;
    const int nnz2 = in_sizes[4] / 2;
    const int nnz3 = in_sizes[7] / 2;
    const int nnz4 = in_sizes[10] / 2;
    const int nnz5 = in_sizes[13] / 2;

    char* ws = (char*)d_ws;
    ushort_t* W1 = (ushort_t*)(ws + O_W1);
    uint_t* bkt  = (uint_t*)(ws + O_BKT);
    float* part  = (float*)(ws + O_PART);
    float* y1 = (float*)(ws + O_Y1);
    float* W2 = (float*)(ws + O_W2);
    float* W3 = (float*)(ws + O_W3);
    float* W4 = (float*)(ws + O_W4);
    float* W5 = (float*)(ws + O_W5);
    int*   cur = (int*)(ws + O_CUR);
    ushort_t* Xb = (ushort_t*)(ws + O_XB);
    float* h1 = (float*)(ws + O_H1);
    float* h2 = (float*)(ws + O_H2);
    float* y3 = (float*)(ws + O_Y3);
    float* h3 = (float*)(ws + O_H3);
    float* y4 = (float*)(ws + O_Y4);
    float* h4 = (float*)(ws + O_H4);

    // 1) zero W2..W5 + bucket cursors (3.07 MB)
    zero_f4<<<dim3((unsigned)((ZERO_BYTES / 16 + 255) / 256)), dim3(256), 0, stream>>>(
        (float4*)(ws + ZERO_OFF), ZERO_BYTES / 16);

    // 2) bucket layer-1 nnz by (row, col/15000)
    reorder<<<dim3((nnz1 + 255) / 256), dim3(256), 0, stream>>>(idx1, val1, nnz1, bkt, cur);

    // 3) stream-fill dense bf16 W1 (600 rows; no pre-zero needed)
    fill_w1<<<dim3(NBKT), dim3(256), 0, stream>>>(bkt, cur, W1);

    // 4) densify small weights
    scatter_f32<<<dim3((nnz2 + 255) / 256), dim3(256), 0, stream>>>(idx2, val2, nnz2, W2, 640);
    scatter_f32<<<dim3((nnz3 + 255) / 256), dim3(256), 0, stream>>>(idx3, val3, nnz3, W3, 640);
    scatter_f32<<<dim3((nnz4 + 255) / 256), dim3(256), 0, stream>>>(idx4, val4, nnz4, W4, 320);
    scatter_f32<<<dim3((nnz5 + 255) / 256), dim3(256), 0, stream>>>(idx5, val5, nnz5, W5, 256);

    // 5) layer 1 in two K-halves: cast half -> MFMA gemm into split-K partials
    cast_half<<<dim3(15000), dim3(256), 0, stream>>>(x, 0, Xb);
    gemm1<<<dim3(20, NSPLIT), dim3(256), 0, stream>>>(Xb, 60000, W1, 0, part, 0);
    cast_half<<<dim3(15000), dim3(256), 0, stream>>>(x, 60000, Xb);
    gemm1<<<dim3(20, NSPLIT), dim3(256), 0, stream>>>(Xb, 60000, W1, 60000, part, 1);

    // 6) reduce partials -> y1
    reduce_part<<<dim3(512 * N1P / 256), dim3(256), 0, stream>>>(part, y1);

    // 7) BN1 + silu (b1 cancels inside BN)
    bn_silu<<<dim3(N1P), dim3(256), 0, stream>>>(y1, N1P, 600, g1, be1, h1);

    // 8) layer 2: silu(h1 @ W2^T + b2)
    small_gemm<1, 0><<<dim3(8, N2P / 64), dim3(256), 0, stream>>>(h1, N1P, W2, 640, b2, 600,
                                                                  h2, N2P, N2P, 640);
    // 9) layer 3 + BN2 + silu (b3 cancels)
    small_gemm<0, 0><<<dim3(8, N3P / 64), dim3(256), 0, stream>>>(h2, N2P, W3, 640, nullptr, 0,
                                                                  y3, N3P, N3P, 640);
    bn_silu<<<dim3(N3P), dim3(256), 0, stream>>>(y3, N3P, 300, g2, be2, h3);

    // 10) layer 4 + BN3 + silu (b4 cancels)
    small_gemm<0, 0><<<dim3(8, N4P / 64), dim3(256), 0, stream>>>(h3, N3P, W4, 320, nullptr, 0,
                                                                  y4, N4P, N4P, 320);
    bn_silu<<<dim3(N4P), dim3(256), 0, stream>>>(y4, N4P, 200, g3, be3, h4);

    // 11) layer 5: h4 @ W5^T + b5 -> d_out (fp32, compact 512x200)
    small_gemm<0, 1><<<dim3(8, N5P / 64), dim3(256), 0, stream>>>(h4, N4P, W5, 256, b5, 200,
                                                                  (float*)d_out, 200, 200, 256);
    (void)n_in; (void)out_size; (void)ws_size;
}

// Round 4
// 1380.737 us; speedup vs baseline: 1.2355x; 1.2355x over previous
//
#include <hip/hip_runtime.h>

typedef unsigned short ushort_t;
typedef unsigned int uint_t;

typedef __bf16 bf16x8 __attribute__((ext_vector_type(8)));
typedef float  floatx4 __attribute__((ext_vector_type(4)));

#define AS3 __attribute__((address_space(3)))
#define AS1 __attribute__((address_space(1)))

// ---------------- dims ----------------
#define BATCH 512
#define D_IN  120000
#define N1P   640   // 600 padded to 5*128 (cols 600-639 masked downstream)
#define N2P   640
#define N3P   320
#define N4P   256
#define N5P   256

// W1 densify pipeline
#define SUBS  8
#define SUBW  15000                 // 8*15000 = 120000
#define NBKT  (600 * SUBS)          // 4800 buckets
#define RBLK  120                   // reorder blocks (7.2M/120 = 60000 entries each)
#define SCAP  40                    // per-(block,bucket) capacity; Poisson(12.5), P(ovfl)~1e-10

// gemm1 split-K (per K-half of 60000): 25 splits * 2400 (=75*32)
#define NSPLIT 25
#define KCHUNK 2400

// ---------------- workspace layout (bytes), total 242,566,144 < proven 280.8 MB ----------------
static constexpr long O_W1  = 0;                          // bf16 [600][120000]
static constexpr long SZ_W1 = 600L * D_IN * 2;            // 144,000,000
// region B (dead after fill_w1):
static constexpr long O_SEG = O_W1 + SZ_W1;               // u32 [120][4800][40] = 92,160,000
static constexpr long SZ_SEG = (long)RBLK * NBKT * SCAP * 4;
static constexpr long O_CNT = O_SEG + SZ_SEG;             // u32 [4800][120] = 2,304,000
static constexpr long SZ_CNT = (long)NBKT * RBLK * 4;
// region C (aliases B; live from cast_half onward):
static constexpr long O_XB  = O_SEG;                      // bf16 [512][60000] = 61,440,000
static constexpr long SZ_XB = 512L * 60000 * 2;
static constexpr long O_PART = O_XB + SZ_XB;              // f32 [25][512][640] = 32,768,000
static constexpr long SZ_PART = (long)NSPLIT * 512 * N1P * 4;
static constexpr long O_Y1  = O_PART + SZ_PART;           // f32 [512][640]
static constexpr long SZ_Y1 = 512L * N1P * 4;
// region D (persistent smalls):
static constexpr long O_W2  = O_Y1 + SZ_Y1;               // f32 [640][640]
static constexpr long SZ_W2 = 640L * 640 * 4;
static constexpr long O_W3  = O_W2 + SZ_W2;               // f32 [320][640]
static constexpr long SZ_W3 = 320L * 640 * 4;
static constexpr long O_W4  = O_W3 + SZ_W3;               // f32 [256][320]
static constexpr long SZ_W4 = 256L * 320 * 4;
static constexpr long O_W5  = O_W4 + SZ_W4;               // f32 [256][256]
static constexpr long SZ_W5 = 256L * 256 * 4;
static constexpr long ZERO_OFF = O_W2;                    // zero W2..W5 (contiguous, 3,047,424 B)
static constexpr long ZERO_BYTES = SZ_W2 + SZ_W3 + SZ_W4 + SZ_W5;
// h-buffers alias part (dead after reduce_part):
static constexpr long O_H1 = O_PART;
static constexpr long O_H2 = O_H1 + 512L * 640 * 4;
static constexpr long O_Y3 = O_H2 + 512L * 640 * 4;
static constexpr long O_H3 = O_Y3 + 512L * 320 * 4;
static constexpr long O_Y4 = O_H3 + 512L * 320 * 4;
static constexpr long O_H4 = O_Y4 + 512L * 256 * 4;

// ---------------- helpers ----------------
__device__ __forceinline__ ushort_t f2bf(float f) {
    union { float f; uint_t u; } x;
    x.f = f;
    uint_t u = x.u;
    return (ushort_t)((u + 0x7FFFu + ((u >> 16) & 1u)) >> 16);  // RNE
}
__device__ __forceinline__ float bf2f(ushort_t h) {
    union { uint_t u; float f; } x;
    x.u = ((uint_t)h) << 16;
    return x.f;
}
__device__ __forceinline__ float silu_f(float z) {
    return z / (1.f + expf(-z));
}
__device__ __forceinline__ void load16_lds(const void* g, void* l) {
    __builtin_amdgcn_global_load_lds((const AS1 char*)g, (AS3 char*)l, 16, 0, 0);
}

// ---------------- zero (W2..W5) ----------------
__global__ void zero_f4(float4* __restrict__ p, long n4) {
    long i = (long)blockIdx.x * blockDim.x + threadIdx.x;
    if (i < n4) p[i] = make_float4(0.f, 0.f, 0.f, 0.f);
}

// ---------------- reorder v2: atomic-free segmented scatter ----------------
// 120 blocks; block handles a contiguous chunk; LDS counters give local ranks;
// each block writes its own seg[blk][bucket][SCAP] region. No global atomics.
__global__ __launch_bounds__(256) void reorder2(const int* __restrict__ idx,
                                                const float* __restrict__ vals, int nnz,
                                                uint_t* __restrict__ seg,
                                                uint_t* __restrict__ cntT) {
    __shared__ uint_t lcnt[NBKT];  // 19.2 KB
    for (int i = threadIdx.x; i < NBKT; i += 256) lcnt[i] = 0;
    __syncthreads();
    const int blk = blockIdx.x;
    const long chunk = (nnz + RBLK - 1) / RBLK;
    long lo = (long)blk * chunk;
    long hi = lo + chunk; if (hi > nnz) hi = nnz;
    uint_t* myseg = seg + (size_t)blk * NBKT * SCAP;
    for (long i = lo + threadIdx.x; i < hi; i += 256) {
        int r = idx[i];
        int c = idx[(long)nnz + i];
        int q = c / SUBW;
        int b = r * SUBS + q;
        int colw = c - q * SUBW;
        uint_t pos = atomicAdd(&lcnt[b], 1u);
        if (pos < SCAP)
            myseg[(size_t)b * SCAP + pos] = ((uint_t)colw << 16) | (uint_t)f2bf(vals[i]);
    }
    __syncthreads();
    for (int b = threadIdx.x; b < NBKT; b += 256) {
        uint_t c = lcnt[b];
        cntT[(size_t)b * RBLK + blk] = (c > SCAP) ? SCAP : c;
    }
}

// ---------------- fill W1: one block per bucket; LDS f32 accumulate -> bf16 stream ----------------
__global__ __launch_bounds__(256) void fill_w1(const uint_t* __restrict__ seg,
                                               const uint_t* __restrict__ cntT,
                                               ushort_t* __restrict__ W) {
    __shared__ float acc[SUBW];      // 60,000 B
    __shared__ uint_t scnt[RBLK];
    const int b = blockIdx.x;
    const int t = threadIdx.x;
    for (int i = t; i < SUBW; i += 256) acc[i] = 0.f;
    if (t < RBLK) scnt[t] = cntT[(size_t)b * RBLK + t];
    __syncthreads();
    for (int s = t; s < RBLK * SCAP; s += 256) {   // 4800 slots, 18.75 iters
        int blk = s / SCAP, slot = s - blk * SCAP;
        if ((uint_t)slot < scnt[blk]) {
            uint_t e = seg[((size_t)blk * NBKT + b) * SCAP + slot];
            atomicAdd(&acc[e >> 16], bf2f((ushort_t)(e & 0xFFFFu)));
        }
    }
    __syncthreads();
    const int r = b >> 3, sub = b & 7;
    ushort_t* dst = W + (size_t)r * D_IN + sub * SUBW;
    for (int i = t; i < SUBW / 8; i += 256) {      // 1875 16B chunks, coalesced
        union { ushort_t us[8]; uint4 v; } u;
#pragma unroll
        for (int k = 0; k < 8; k++) u.us[k] = f2bf(acc[i * 8 + k]);
        ((uint4*)dst)[i] = u.v;
    }
}

// ---------------- scatter small layers into dense fp32 W ----------------
__global__ void scatter_f32(const int* __restrict__ idx, const float* __restrict__ vals,
                            int nnz, float* __restrict__ W, int ldw) {
    int i = blockIdx.x * blockDim.x + threadIdx.x;
    if (i >= nnz) return;
    atomicAdd(&W[(size_t)idx[i] * ldw + idx[nnz + i]], vals[i]);
}

// ---------------- cast one K-half of x: fp32 -> bf16 [512][60000] ----------------
__global__ void cast_half(const float* __restrict__ X, int kbase, ushort_t* __restrict__ Xb) {
    long t = (long)blockIdx.x * blockDim.x + threadIdx.x;
    if (t >= (long)BATCH * 7500) return;
    int row = (int)(t / 7500);
    int c8 = (int)(t - (long)row * 7500);
    const float4* s = (const float4*)(X + (size_t)row * D_IN + kbase + c8 * 8);
    float4 a = s[0], bb = s[1];
    union { ushort_t us[8]; uint4 v; } u;
    u.us[0] = f2bf(a.x);  u.us[1] = f2bf(a.y);  u.us[2] = f2bf(a.z);  u.us[3] = f2bf(a.w);
    u.us[4] = f2bf(bb.x); u.us[5] = f2bf(bb.y); u.us[6] = f2bf(bb.z); u.us[7] = f2bf(bb.w);
    ((uint4*)Xb)[t] = u.v;
}

// ---------------- GEMM1 half: split-K partials ----------------
// grid = (20 tiles = 4m x 5n, 25 splits), block = 256
__global__ __launch_bounds__(256) void gemm1(const ushort_t* __restrict__ X, int ldx,
                                             const ushort_t* __restrict__ W, int kwbase,
                                             float* __restrict__ P, int accum) {
    __shared__ ushort_t sA[128 * 32];
    __shared__ ushort_t sB[128 * 32];

    const int tile = blockIdx.x;
    const int bm = tile / 5, bn = tile % 5;
    const int ks = blockIdx.y * KCHUNK;

    const int t = threadIdx.x;
    const int lane = t & 63;
    const int w = t >> 6;
    const int wm = w >> 1, wn = w & 1;

    const int c0 = w * 128 + lane;
    const int c1 = c0 + 64;
    const int rA0 = c0 >> 2, qA0 = c0 & 3;
    const int rA1 = c1 >> 2, qA1 = c1 & 3;

    const ushort_t* pa0 = X + (size_t)(bm * 128 + rA0) * ldx + ks + qA0 * 8;
    const ushort_t* pa1 = X + (size_t)(bm * 128 + rA1) * ldx + ks + qA1 * 8;
    const ushort_t* pb0 = W + (size_t)(bn * 128 + rA0) * D_IN + kwbase + ks + qA0 * 8;
    const ushort_t* pb1 = W + (size_t)(bn * 128 + rA1) * D_IN + kwbase + ks + qA1 * 8;

    ushort_t* la0 = sA + (size_t)(w * 128) * 8;
    ushort_t* la1 = sA + (size_t)(w * 128 + 64) * 8;
    ushort_t* lb0 = sB + (size_t)(w * 128) * 8;
    ushort_t* lb1 = sB + (size_t)(w * 128 + 64) * 8;

    const int i16 = lane & 15;
    const int qk = lane >> 4;
    const bf16x8* ap[4];
    const bf16x8* bp[4];
#pragma unroll
    for (int mi = 0; mi < 4; mi++)
        ap[mi] = (const bf16x8*)&sA[(size_t)(wm * 64 + mi * 16 + i16) * 32 + qk * 8];
#pragma unroll
    for (int ni = 0; ni < 4; ni++)
        bp[ni] = (const bf16x8*)&sB[(size_t)(wn * 64 + ni * 16 + i16) * 32 + qk * 8];

    floatx4 acc[4][4] = {};

    for (int it = 0; it < KCHUNK / 32; ++it) {
        __syncthreads();
        load16_lds(pa0, la0);
        load16_lds(pa1, la1);
        load16_lds(pb0, lb0);
        load16_lds(pb1, lb1);
        pa0 += 32; pa1 += 32; pb0 += 32; pb1 += 32;
        __syncthreads();

        bf16x8 af[4], bfr[4];
#pragma unroll
        for (int mi = 0; mi < 4; mi++) af[mi] = *ap[mi];
#pragma unroll
        for (int ni = 0; ni < 4; ni++) bfr[ni] = *bp[ni];
#pragma unroll
        for (int mi = 0; mi < 4; mi++)
#pragma unroll
            for (int ni = 0; ni < 4; ni++)
                acc[mi][ni] = __builtin_amdgcn_mfma_f32_16x16x32_bf16(af[mi], bfr[ni], acc[mi][ni], 0, 0, 0);
    }

    float* Pp = P + (size_t)blockIdx.y * (512 * N1P);
#pragma unroll
    for (int mi = 0; mi < 4; mi++) {
#pragma unroll
        for (int ni = 0; ni < 4; ni++) {
#pragma unroll
            for (int r = 0; r < 4; r++) {
                int row = bm * 128 + wm * 64 + mi * 16 + qk * 4 + r;
                int col = bn * 128 + wn * 64 + ni * 16 + i16;
                size_t o = (size_t)row * N1P + col;
                if (accum) Pp[o] += acc[mi][ni][r];
                else       Pp[o]  = acc[mi][ni][r];
            }
        }
    }
}

// ---------------- reduce split-K partials -> y1 ----------------
__global__ void reduce_part(const float* __restrict__ P, float* __restrict__ Y) {
    int i = blockIdx.x * 256 + threadIdx.x;
    float s = 0.f;
#pragma unroll
    for (int k = 0; k < NSPLIT; k++) s += P[(size_t)k * (512 * N1P) + i];
    Y[i] = s;
}

// ---------------- BatchNorm (training, biased var) + SiLU, per-column ----------------
__global__ void bn_silu(const float* __restrict__ Y, int ld, int realN,
                        const float* __restrict__ g, const float* __restrict__ be,
                        float* __restrict__ H) {
    int j = blockIdx.x;
    int t = threadIdx.x;
    if (j >= realN) {
        for (int b = t; b < BATCH; b += 256) H[(size_t)b * ld + j] = 0.f;
        return;
    }
    float v0 = Y[(size_t)t * ld + j];
    float v1 = Y[(size_t)(t + 256) * ld + j];
    __shared__ float rs[256], rss[256];
    rs[t] = v0 + v1;
    rss[t] = v0 * v0 + v1 * v1;
    __syncthreads();
    for (int o = 128; o > 0; o >>= 1) {
        if (t < o) { rs[t] += rs[t + o]; rss[t] += rss[t + o]; }
        __syncthreads();
    }
    float mean = rs[0] * (1.f / 512.f);
    float var  = rss[0] * (1.f / 512.f) - mean * mean;
    float sc = rsqrtf(var + 1e-5f) * g[j];
    float sh = be[j] - mean * sc;
    H[(size_t)t * ld + j]         = silu_f(v0 * sc + sh);
    H[(size_t)(t + 256) * ld + j] = silu_f(v1 * sc + sh);
}

// ---------------- small fp32 GEMM: C(512 x N) = A(512 x K) @ W^T(N x K) ----------------
template <int ACT, int GUARD>
__global__ __launch_bounds__(256) void small_gemm(const float* __restrict__ A, int lda,
                                                  const float* __restrict__ W, int ldw,
                                                  const float* __restrict__ bias, int biasN,
                                                  float* __restrict__ out, int ldo, int outN,
                                                  int K) {
    __shared__ float sA[64][20];
    __shared__ float sB[64][20];
    const int t = threadIdx.x;
    const int m0 = blockIdx.x * 64, n0 = blockIdx.y * 64;
    const int ty = t >> 4, tx = t & 15;
    const int lm = t >> 2, lq = t & 3;
    float acc[4][4] = {};

    for (int kt = 0; kt < K; kt += 16) {
        __syncthreads();
        float4 av = *(const float4*)&A[(size_t)(m0 + lm) * lda + kt + lq * 4];
        float4 wv = *(const float4*)&W[(size_t)(n0 + lm) * ldw + kt + lq * 4];
        sA[lm][lq * 4 + 0] = av.x; sA[lm][lq * 4 + 1] = av.y;
        sA[lm][lq * 4 + 2] = av.z; sA[lm][lq * 4 + 3] = av.w;
        sB[lm][lq * 4 + 0] = wv.x; sB[lm][lq * 4 + 1] = wv.y;
        sB[lm][lq * 4 + 2] = wv.z; sB[lm][lq * 4 + 3] = wv.w;
        __syncthreads();
#pragma unroll
        for (int kg = 0; kg < 4; kg++) {
            float4 a4[4], b4[4];
#pragma unroll
            for (int i = 0; i < 4; i++) a4[i] = *(const float4*)&sA[ty * 4 + i][kg * 4];
#pragma unroll
            for (int j = 0; j < 4; j++) b4[j] = *(const float4*)&sB[tx * 4 + j][kg * 4];
#pragma unroll
            for (int i = 0; i < 4; i++)
#pragma unroll
                for (int j = 0; j < 4; j++)
                    acc[i][j] += a4[i].x * b4[j].x + a4[i].y * b4[j].y +
                                 a4[i].z * b4[j].z + a4[i].w * b4[j].w;
        }
    }

#pragma unroll
    for (int i = 0; i < 4; i++) {
#pragma unroll
        for (int j = 0; j < 4; j++) {
            int row = m0 + ty * 4 + i;
            int col = n0 + tx * 4 + j;
            float v = acc[i][j];
            if (bias != nullptr && col < biasN) v += bias[col];
            if (ACT == 1) v = silu_f(v);
            if (GUARD) {
                if (col < outN) out[(size_t)row * ldo + col] = v;
            } else {
                out[(size_t)row * ldo + col] = v;
            }
        }
    }
}

// ---------------- launch ----------------
extern "C" void kernel_launch(void* const* d_in, const int* in_sizes, int n_in,
                              void* d_out, int out_size, void* d_ws, size_t ws_size,
                              hipStream_t stream) {
    const float* x   = (const float*)d_in[0];
    const int* idx1 = (const int*)d_in[1];  const float* val1 = (const float*)d_in[2];
    const int* idx2 = (const int*)d_in[4];  const float* val2 = (const float*)d_in[5];
    const float* b2 = (const float*)d_in[6];
    const int* idx3 = (const int*)d_in[7];  const float* val3 = (const float*)d_in[8];
    const int* idx4 = (const int*)d_in[10]; const float* val4 = (const float*)d_in[11];
    const int* idx5 = (const int*)d_in[13]; const float* val5 = (const float*)d_in[14];
    const float* b5 = (const float*)d_in[15];
    const float* g1 = (const float*)d_in[16]; const float* be1 = (const float*)d_in[17];
    const float* g2 = (const float*)d_in[18]; const float* be2 = (const float*)d_in[19];
    const float* g3 = (const float*)d_in[20]; const float* be3 = (const float*)d_in[21];

    const int nnz1 = in_sizes[1] / 2;
    const int nnz2 = in_sizes[4] / 2;
    const int nnz3 = in_sizes[7] / 2;
    const int nnz4 = in_sizes[10] / 2;
    const int nnz5 = in_sizes[13] / 2;

    char* ws = (char*)d_ws;
    ushort_t* W1 = (ushort_t*)(ws + O_W1);
    uint_t* seg  = (uint_t*)(ws + O_SEG);
    uint_t* cntT = (uint_t*)(ws + O_CNT);
    ushort_t* Xb = (ushort_t*)(ws + O_XB);
    float* part  = (float*)(ws + O_PART);
    float* y1 = (float*)(ws + O_Y1);
    float* W2 = (float*)(ws + O_W2);
    float* W3 = (float*)(ws + O_W3);
    float* W4 = (float*)(ws + O_W4);
    float* W5 = (float*)(ws + O_W5);
    float* h1 = (float*)(ws + O_H1);
    float* h2 = (float*)(ws + O_H2);
    float* y3 = (float*)(ws + O_Y3);
    float* h3 = (float*)(ws + O_H3);
    float* y4 = (float*)(ws + O_Y4);
    float* h4 = (float*)(ws + O_H4);

    // 1) zero W2..W5 (3.05 MB)
    zero_f4<<<dim3((unsigned)((ZERO_BYTES / 16 + 255) / 256)), dim3(256), 0, stream>>>(
        (float4*)(ws + ZERO_OFF), ZERO_BYTES / 16);

    // 2) segmented reorder (no global atomics)
    reorder2<<<dim3(RBLK), dim3(256), 0, stream>>>(idx1, val1, nnz1, seg, cntT);

    // 3) stream-fill dense bf16 W1
    fill_w1<<<dim3(NBKT), dim3(256), 0, stream>>>(seg, cntT, W1);

    // 4) densify small weights
    scatter_f32<<<dim3((nnz2 + 255) / 256), dim3(256), 0, stream>>>(idx2, val2, nnz2, W2, 640);
    scatter_f32<<<dim3((nnz3 + 255) / 256), dim3(256), 0, stream>>>(idx3, val3, nnz3, W3, 640);
    scatter_f32<<<dim3((nnz4 + 255) / 256), dim3(256), 0, stream>>>(idx4, val4, nnz4, W4, 320);
    scatter_f32<<<dim3((nnz5 + 255) / 256), dim3(256), 0, stream>>>(idx5, val5, nnz5, W5, 256);

    // 5) layer 1 in two K-halves: cast half -> MFMA gemm into split-K partials
    cast_half<<<dim3(15000), dim3(256), 0, stream>>>(x, 0, Xb);
    gemm1<<<dim3(20, NSPLIT), dim3(256), 0, stream>>>(Xb, 60000, W1, 0, part, 0);
    cast_half<<<dim3(15000), dim3(256), 0, stream>>>(x, 60000, Xb);
    gemm1<<<dim3(20, NSPLIT), dim3(256), 0, stream>>>(Xb, 60000, W1, 60000, part, 1);

    // 6) reduce partials -> y1
    reduce_part<<<dim3(512 * N1P / 256), dim3(256), 0, stream>>>(part, y1);

    // 7) BN1 + silu (b1 cancels inside BN)
    bn_silu<<<dim3(N1P), dim3(256), 0, stream>>>(y1, N1P, 600, g1, be1, h1);

    // 8) layer 2: silu(h1 @ W2^T + b2)
    small_gemm<1, 0><<<dim3(8, N2P / 64), dim3(256), 0, stream>>>(h1, N1P, W2, 640, b2, 600,
                                                                  h2, N2P, N2P, 640);
    // 9) layer 3 + BN2 + silu (b3 cancels)
    small_gemm<0, 0><<<dim3(8, N3P / 64), dim3(256), 0, stream>>>(h2, N2P, W3, 640, nullptr, 0,
                                                                  y3, N3P, N3P, 640);
    bn_silu<<<dim3(N3P), dim3(256), 0, stream>>>(y3, N3P, 300, g2, be2, h3);

    // 10) layer 4 + BN3 + silu (b4 cancels)
    small_gemm<0, 0><<<dim3(8, N4P / 64), dim3(256), 0, stream>>>(h3, N3P, W4, 320, nullptr, 0,
                                                                  y4, N4P, N4P, 320);
    bn_silu<<<dim3(N4P), dim3(256), 0, stream>>>(y4, N4P, 200, g3, be3, h4);

    // 11) layer 5: h4 @ W5^T + b5 -> d_out (fp32, compact 512x200)
    small_gemm<0, 1><<<dim3(8, N5P / 64), dim3(256), 0, stream>>>(h4, N4P, W5, 256, b5, 200,
                                                                  (float*)d_out, 200, 200, 256);
    (void)n_in; (void)out_size; (void)ws_size;
}